// Round 1
// baseline (2873.073 us; speedup 1.0000x reference)
//
#include <hip/hip_runtime.h>
#include <hip/hip_bf16.h>

typedef _Float16 half8 __attribute__((ext_vector_type(8)));
typedef float floatx4 __attribute__((ext_vector_type(4)));

#define T_STEPS 20
#define NSEQ 131072
#define HID 192
#define G4 768
#define ROWS 64
#define HPAD 200  // fp16 elems per LDS row: 400B stride, 16B-aligned, 2-way banks (free)

// Prologue: convert w_hh [768][192] f32 -> fp16 in workspace (re-done every call:
// d_ws is re-poisoned before each timed launch).
__global__ void cvt_whh_f16(const float* __restrict__ whh, _Float16* __restrict__ out16) {
    int i = blockIdx.x * 256 + threadIdx.x;
    if (i < G4 * HID) out16[i] = (_Float16)whh[i];
}

__global__ __launch_bounds__(768) void lstm_fused_kernel(
    const float* __restrict__ obs,       // [20][N][2]
    const float* __restrict__ h0,        // [N][192]
    const float* __restrict__ w_ih,      // [768][2]
    const float* __restrict__ b_ih,      // [768]
    const float* __restrict__ b_hh,      // [768]
    const float* __restrict__ w_out,     // [2][192]
    const float* __restrict__ b_out,     // [2]
    const _Float16* __restrict__ whh16,  // [768][192] fp16
    float* __restrict__ out)             // [20][N][2]
{
    __shared__ _Float16 h_lds[ROWS][HPAD];
    __shared__ float x_lds[ROWS][2];
    __shared__ float wih0[G4], wih1[G4], bsum[G4];
    __shared__ float wout_s[2][HID];
    __shared__ float bout_s[2];

    const int tid  = threadIdx.x;
    const int wave = tid >> 6;       // 0..11
    const int lane = tid & 63;
    const int quad = lane >> 4;      // 0..3
    const int l16  = lane & 15;
    const int ht   = wave;           // hidden tile 0..11 (16 units each)
    const int base = blockIdx.x * ROWS;

    // ---- one-time staging ----
    for (int i = tid; i < G4; i += 768) {
        wih0[i] = w_ih[2 * i];
        wih1[i] = w_ih[2 * i + 1];
        bsum[i] = b_ih[i] + b_hh[i];
    }
    if (tid < 2 * HID) wout_s[tid / HID][tid % HID] = w_out[tid];
    if (tid < 2) bout_s[tid] = b_out[tid];

    for (int i = tid; i < ROWS * HID; i += 768) {
        int r = i / HID, k = i - r * HID;
        h_lds[r][k] = (_Float16)h0[(size_t)(base + r) * HID + k];
    }

    float c[16];
#pragma unroll
    for (int i = 0; i < 16; ++i) c[i] = 0.f;

    __syncthreads();

    for (int t = 0; t < T_STEPS; ++t) {
        const int src = (t == 0) ? 0 : (t - 1);
        if (tid < 2 * ROWS) {
            x_lds[tid >> 1][tid & 1] = obs[(size_t)src * NSEQ * 2 + (size_t)base * 2 + tid];
        }
        __syncthreads();   // S1: x staged; h_lds stable (written before prev S1)

        // ---- gates[64][768] tile: wave ht owns cols {g*192 + ht*16 + n} ----
        floatx4 acc[4][4];
#pragma unroll
        for (int rt = 0; rt < 4; ++rt)
#pragma unroll
            for (int g = 0; g < 4; ++g)
                acc[rt][g] = (floatx4){0.f, 0.f, 0.f, 0.f};

#pragma unroll
        for (int kc = 0; kc < 6; ++kc) {
            half8 afrag[4];
#pragma unroll
            for (int rt = 0; rt < 4; ++rt)
                afrag[rt] = *(const half8*)&h_lds[rt * 16 + l16][kc * 32 + quad * 8];
#pragma unroll
            for (int g = 0; g < 4; ++g) {
                const int col = g * HID + ht * 16 + l16;
                half8 bfrag = *(const half8*)&whh16[(size_t)col * HID + kc * 32 + quad * 8];
#pragma unroll
                for (int rt = 0; rt < 4; ++rt)
                    acc[rt][g] = __builtin_amdgcn_mfma_f32_16x16x32_f16(
                        afrag[rt], bfrag, acc[rt][g], 0, 0, 0);
            }
        }

        __syncthreads();   // S2: all waves done reading h_lds; safe to overwrite

        // ---- activation: wave-local i/f/g/o for hidden unit j ----
        const int j = ht * 16 + l16;
        const float bi = bsum[j],           w0i = wih0[j],           w1i = wih1[j];
        const float bf = bsum[HID + j],     w0f = wih0[HID + j],     w1f = wih1[HID + j];
        const float bg = bsum[2 * HID + j], w0g = wih0[2 * HID + j], w1g = wih1[2 * HID + j];
        const float bo = bsum[3 * HID + j], w0o = wih0[3 * HID + j], w1o = wih1[3 * HID + j];

#pragma unroll
        for (int rt = 0; rt < 4; ++rt) {
#pragma unroll
            for (int r = 0; r < 4; ++r) {
                const int row = rt * 16 + quad * 4 + r;
                const float x0 = x_lds[row][0], x1 = x_lds[row][1];
                const float gi = acc[rt][0][r] + bi + x0 * w0i + x1 * w1i;
                const float gf = acc[rt][1][r] + bf + x0 * w0f + x1 * w1f;
                const float gg = acc[rt][2][r] + bg + x0 * w0g + x1 * w1g;
                const float go = acc[rt][3][r] + bo + x0 * w0o + x1 * w1o;
                const float ii = 1.f / (1.f + __expf(-gi));
                const float ff = 1.f / (1.f + __expf(-gf));
                const float eg = __expf(2.f * gg);
                const float tg = 1.f - 2.f / (eg + 1.f);       // tanh, overflow-safe
                const float oo = 1.f / (1.f + __expf(-go));
                const int ci = rt * 4 + r;
                const float cn = ff * c[ci] + ii * tg;
                c[ci] = cn;
                const float ec = __expf(2.f * cn);
                const float tc = 1.f - 2.f / (ec + 1.f);
                const float hn = oo * tc;
                h_lds[row][j] = (_Float16)hn;                   // c stays fp32 in regs
            }
        }
        __syncthreads();   // S3: h_new complete in LDS

        // ---- out = h_new @ w_out.T + b_out : 8 threads per row ----
        if (tid < 512) {
            const int row = tid >> 3;
            const int sub = tid & 7;
            const int k0 = sub * 24;
            float p0 = 0.f, p1 = 0.f;
#pragma unroll
            for (int v = 0; v < 3; ++v) {
                half8 hv = *(const half8*)&h_lds[row][k0 + v * 8];
#pragma unroll
                for (int jj = 0; jj < 8; ++jj) {
                    const float hf = (float)hv[jj];
                    p0 += hf * wout_s[0][k0 + v * 8 + jj];
                    p1 += hf * wout_s[1][k0 + v * 8 + jj];
                }
            }
#pragma unroll
            for (int d = 1; d < 8; d <<= 1) {
                p0 += __shfl_down(p0, d);
                p1 += __shfl_down(p1, d);
            }
            if (sub == 0) {
                const size_t o = ((size_t)t * NSEQ + base + row) * 2;
                float2 val = make_float2(p0 + bout_s[0], p1 + bout_s[1]);
                *(float2*)&out[o] = val;
            }
        }
        // next iteration's S1 orders these h_lds reads before the next overwrite
    }
}

extern "C" void kernel_launch(void* const* d_in, const int* in_sizes, int n_in,
                              void* d_out, int out_size, void* d_ws, size_t ws_size,
                              hipStream_t stream) {
    const float* obs  = (const float*)d_in[0];
    const float* h0   = (const float*)d_in[1];
    const float* wih  = (const float*)d_in[2];
    const float* whh  = (const float*)d_in[3];
    const float* bih  = (const float*)d_in[4];
    const float* bhh  = (const float*)d_in[5];
    const float* wout = (const float*)d_in[6];
    const float* bout = (const float*)d_in[7];
    float* out = (float*)d_out;
    _Float16* whh16 = (_Float16*)d_ws;   // 294912 B

    cvt_whh_f16<<<(G4 * HID + 255) / 256, 256, 0, stream>>>(whh, whh16);
    lstm_fused_kernel<<<NSEQ / ROWS, 768, 0, stream>>>(
        obs, h0, wih, bih, bhh, wout, bout, whh16, out);
}